// Round 8
// baseline (370.941 us; speedup 1.0000x reference)
//
#include <hip/hip_runtime.h>

#define EPS 1e-7f
#define CCH 42
#define NCON 8

typedef float v4f __attribute__((ext_vector_type(4)));

// ---------------------------------------------------------------------------
// Per-channel MLP (dims NIN -> 5 -> 4 -> 4 -> 3) + 3-way softmax.
// `c` is wave-uniform, so weight/bias loads compile to s_load and FMAs take
// the weight operand from SGPRs.
// ---------------------------------------------------------------------------
template<int NIN>
__device__ __forceinline__ void mlp_softmax3(
    const float x[NIN], int c,
    const float* __restrict__ W0, const float* __restrict__ b0,
    const float* __restrict__ W1, const float* __restrict__ b1,
    const float* __restrict__ W2, const float* __restrict__ b2,
    const float* __restrict__ W3, const float* __restrict__ b3,
    float o[3])
{
    float h0[5];
#pragma unroll
    for (int j = 0; j < 5; ++j) {
        const float* w = W0 + (c * 5 + j) * NIN;
        float a = b0[c * 5 + j];
#pragma unroll
        for (int i = 0; i < NIN; ++i) a = fmaf(x[i], w[i], a);
        h0[j] = fmaxf(a, 0.0f);
    }
    float h1[4];
#pragma unroll
    for (int j = 0; j < 4; ++j) {
        const float* w = W1 + (c * 4 + j) * 5;
        float a = b1[c * 4 + j];
#pragma unroll
        for (int i = 0; i < 5; ++i) a = fmaf(h0[i], w[i], a);
        h1[j] = fmaxf(a, 0.0f);
    }
    float h2[4];
#pragma unroll
    for (int j = 0; j < 4; ++j) {
        const float* w = W2 + (c * 4 + j) * 4;
        float a = b2[c * 4 + j];
#pragma unroll
        for (int i = 0; i < 4; ++i) a = fmaf(h1[i], w[i], a);
        h2[j] = fmaxf(a, 0.0f);
    }
    float lg[3];
#pragma unroll
    for (int j = 0; j < 3; ++j) {
        const float* w = W3 + (c * 3 + j) * 4;
        float a = b3[c * 3 + j];
#pragma unroll
        for (int i = 0; i < 4; ++i) a = fmaf(h2[i], w[i], a);
        lg[j] = a;
    }
    float m = fmaxf(fmaxf(lg[0], lg[1]), lg[2]);
    float e0 = __expf(lg[0] - m);
    float e1 = __expf(lg[1] - m);
    float e2 = __expf(lg[2] - m);
    float r = __fdividef(1.0f, e0 + e1 + e2);
    o[0] = e0 * r;
    o[1] = e1 * r;
    o[2] = e2 * r;
}

// ---------------------------------------------------------------------------
// Fused kernel, software-pipelined + interleaved. grid = (N/64, 2).
// Block = 384 thr / 6 waves, 64 samples, one output slice (y=0 direct,
// y=1 diffuse), plus a 1344-element tau chunk ALIGNED to its own samples.
//   Issue order (vmcnt is in-order): cons+mu+phaseC-mu FIRST, then the 8 tau
//   nt-loads. Consuming batch `it` then waits only a counted vmcnt while
//   younger tau batches stay in flight.
//   Phase A: per channel ci: MLP -> flat LDS tile; for ci in 2..5 also
//   consume tau batch ci-2 (sum -> 2 exps -> nt stores) -> stores spread
//   across the VALU phase instead of bunching at block end.
//   Phase B: flat v4f LDS -> contiguous 16 B nt stores (full sectors).
// ---------------------------------------------------------------------------
__global__ __launch_bounds__(384, 6) void k_fused(
    const float* __restrict__ tau,
    const float* __restrict__ mu_direct,
    const float* __restrict__ mu_diffuse,
    const float* __restrict__ cons,
    const float* __restrict__ Wd0, const float* __restrict__ bd0,
    const float* __restrict__ Wf0, const float* __restrict__ bf0,
    const float* __restrict__ Wd1, const float* __restrict__ bd1,
    const float* __restrict__ Wf1, const float* __restrict__ bf1,
    const float* __restrict__ Wd2, const float* __restrict__ bd2,
    const float* __restrict__ Wf2, const float* __restrict__ bf2,
    const float* __restrict__ Wd3, const float* __restrict__ bd3,
    const float* __restrict__ Wf3, const float* __restrict__ bf3,
    float* __restrict__ out, int N)
{
    __shared__ __align__(16) float es[64 * 126];
    const int tid  = threadIdx.x;
    const int lane = tid & 63;
    const int wave = tid >> 6;
    const int n0   = blockIdx.x * 64;
    const int n    = n0 + lane;
    const bool direct = (blockIdx.y == 0);
    const size_t nctot = (size_t)N * CCH;

    // phase-C chunk: this block's own samples (n0..n0+63), half per y-slice
    const int per    = 32 * CCH;                    // 1344
    const int base_e = blockIdx.x * (64 * CCH) + (direct ? 0 : per);

    // ---- issue ALL phase-A/C scalar inputs first (oldest in vmcnt order) ----
    float4 c0 = *(const float4*)(cons + (size_t)n * NCON);
    float4 c1 = *(const float4*)(cons + (size_t)n * NCON + 4);
    float mu  = direct ? mu_direct[n] : 0.0f;
    float mdv[4], mfv[4];
#pragma unroll
    for (int it = 0; it < 4; ++it) {
        int off = it * 384 + tid;
        if (off < per) {
            int nn = (base_e + off) / CCH;
            mdv[it] = mu_direct[nn];
            mfv[it] = mu_diffuse[nn];
        }
    }
    __builtin_amdgcn_sched_barrier(0);   // pin: scalar inputs before tau loads

    // ---- then the tau-chunk nt loads (younger; stay in flight) ----
    v4f ta[4], tb[4];
#pragma unroll
    for (int it = 0; it < 4; ++it) {
        int off = it * 384 + tid;
        if (off < per) {
            const v4f* t4 = (const v4f*)tau + ((size_t)base_e + off) * 2;
            ta[it] = __builtin_nontemporal_load(t4);
            tb[it] = __builtin_nontemporal_load(t4 + 1);
        }
    }
    __builtin_amdgcn_sched_barrier(0);   // pin: tau loads issued before phase A

    // ---- Phase A (+ interleaved phase C consumption) ----
    float x[9] = {c0.x, c0.y, c0.z, c0.w, c1.x, c1.y, c1.z, c1.w, 0.0f};
    if (direct) {
        float inv = __fdividef(1.0f, mu + EPS);
#pragma unroll
        for (int i = 0; i < 8; ++i) x[i] *= inv;
        x[8] = mu;
    }
#pragma unroll 1
    for (int ci = 0; ci < 7; ++ci) {
        int c = __builtin_amdgcn_readfirstlane(wave * 7 + ci);
        float o[3];
        if (direct)
            mlp_softmax3<9>(x, c, Wd0, bd0, Wd1, bd1, Wd2, bd2, Wd3, bd3, o);
        else
            mlp_softmax3<8>(x, c, Wf0, bf0, Wf1, bf1, Wf2, bf2, Wf3, bf3, o);
#pragma unroll
        for (int k = 0; k < 3; ++k) es[lane * 126 + c * 3 + k] = o[k];

        // consume tau batch it = ci-2 during channels 2..5
        if (ci >= 2 && ci <= 5) {
            int it = ci - 2;
            int off = it * 384 + tid;
            if (off < per) {
                int e = base_e + off;
                v4f a = ta[it & 3];
                v4f b = tb[it & 3];
                float s = ((a.x + a.y) + (a.z + a.w)) + ((b.x + b.y) + (b.z + b.w));
                float md = mdv[it & 3] + EPS;
                float mf = mfv[it & 3] + EPS;
                __builtin_nontemporal_store(__expf(__fdividef(-s, md)), out + e);
                __builtin_nontemporal_store(__expf(__fdividef(-s, mf)), out + nctot + e);
            }
        }
    }
    __syncthreads();

    // ---- Phase B: flat v4f writeout of the 64x126 tile (2016 x 16 B) ----
    float* base = out + (direct ? 2 : 5) * nctot + (size_t)n0 * (CCH * 3);
#pragma unroll
    for (int iter = 0; iter < 6; ++iter) {
        int idx = iter * 384 + tid;
        if (idx < 2016) {
            v4f v = ((const v4f*)es)[idx];
            __builtin_nontemporal_store(v, (v4f*)base + idx);
        }
    }
}

extern "C" void kernel_launch(void* const* d_in, const int* in_sizes, int n_in,
                              void* d_out, int out_size, void* d_ws, size_t ws_size,
                              hipStream_t stream) {
    const float* tau  = (const float*)d_in[0];
    const float* mud  = (const float*)d_in[1];
    const float* muf  = (const float*)d_in[2];
    const float* cons = (const float*)d_in[3];
    // setup_inputs() dict order: Wd{i}, bd{i}, Wf{i}, bf{i} interleaved per layer.
    const float* Wd0 = (const float*)d_in[4];  const float* bd0 = (const float*)d_in[5];
    const float* Wf0 = (const float*)d_in[6];  const float* bf0 = (const float*)d_in[7];
    const float* Wd1 = (const float*)d_in[8];  const float* bd1 = (const float*)d_in[9];
    const float* Wf1 = (const float*)d_in[10]; const float* bf1 = (const float*)d_in[11];
    const float* Wd2 = (const float*)d_in[12]; const float* bd2 = (const float*)d_in[13];
    const float* Wf2 = (const float*)d_in[14]; const float* bf2 = (const float*)d_in[15];
    const float* Wd3 = (const float*)d_in[16]; const float* bd3 = (const float*)d_in[17];
    const float* Wf3 = (const float*)d_in[18]; const float* bf3 = (const float*)d_in[19];
    float* out = (float*)d_out;

    int N = in_sizes[1];            // mu_direct element count = N
    dim3 grid(N / 64, 2);
    k_fused<<<grid, 384, 0, stream>>>(tau, mud, muf, cons,
                                      Wd0, bd0, Wf0, bf0,
                                      Wd1, bd1, Wf1, bf1,
                                      Wd2, bd2, Wf2, bf2,
                                      Wd3, bd3, Wf3, bf3,
                                      out, N);
}

// Round 9
// 312.053 us; speedup vs baseline: 1.1887x; 1.1887x over previous
//
#include <hip/hip_runtime.h>

#define EPS 1e-7f
#define CCH 42
#define NCON 8

typedef float v4f __attribute__((ext_vector_type(4)));
typedef float v2f __attribute__((ext_vector_type(2)));

// ---------------------------------------------------------------------------
// Per-channel MLP (dims NIN -> 5 -> 4 -> 4 -> 3) + 3-way softmax.
// `c` is wave-uniform, so weight/bias loads compile to s_load and FMAs take
// the weight operand from SGPRs.
// ---------------------------------------------------------------------------
template<int NIN>
__device__ __forceinline__ void mlp_softmax3(
    const float x[NIN], int c,
    const float* __restrict__ W0, const float* __restrict__ b0,
    const float* __restrict__ W1, const float* __restrict__ b1,
    const float* __restrict__ W2, const float* __restrict__ b2,
    const float* __restrict__ W3, const float* __restrict__ b3,
    float o[3])
{
    float h0[5];
#pragma unroll
    for (int j = 0; j < 5; ++j) {
        const float* w = W0 + (c * 5 + j) * NIN;
        float a = b0[c * 5 + j];
#pragma unroll
        for (int i = 0; i < NIN; ++i) a = fmaf(x[i], w[i], a);
        h0[j] = fmaxf(a, 0.0f);
    }
    float h1[4];
#pragma unroll
    for (int j = 0; j < 4; ++j) {
        const float* w = W1 + (c * 4 + j) * 5;
        float a = b1[c * 4 + j];
#pragma unroll
        for (int i = 0; i < 5; ++i) a = fmaf(h0[i], w[i], a);
        h1[j] = fmaxf(a, 0.0f);
    }
    float h2[4];
#pragma unroll
    for (int j = 0; j < 4; ++j) {
        const float* w = W2 + (c * 4 + j) * 4;
        float a = b2[c * 4 + j];
#pragma unroll
        for (int i = 0; i < 4; ++i) a = fmaf(h1[i], w[i], a);
        h2[j] = fmaxf(a, 0.0f);
    }
    float lg[3];
#pragma unroll
    for (int j = 0; j < 3; ++j) {
        const float* w = W3 + (c * 3 + j) * 4;
        float a = b3[c * 3 + j];
#pragma unroll
        for (int i = 0; i < 4; ++i) a = fmaf(h2[i], w[i], a);
        lg[j] = a;
    }
    float m = fmaxf(fmaxf(lg[0], lg[1]), lg[2]);
    float e0 = __expf(lg[0] - m);
    float e1 = __expf(lg[1] - m);
    float e2 = __expf(lg[2] - m);
    float r = __fdividef(1.0f, e0 + e1 + e2);
    o[0] = e0 * r;
    o[1] = e1 * r;
    o[2] = e2 * r;
}

// Phase C: consume prefetched tau regs -> 2 exps -> nt stores.
// All indices static after inlining (#pragma unroll) -- no scratch (rule #20).
__device__ __forceinline__ void phase_c(
    const v4f ta[4], const v4f tb[4],
    const float* __restrict__ mu_direct, const float* __restrict__ mu_diffuse,
    float* __restrict__ out, size_t nctot, int base_e, int per, int tid)
{
#pragma unroll
    for (int it = 0; it < 4; ++it) {
        int off = it * 384 + tid;
        if (off < per) {
            int e = base_e + off;
            v4f a = ta[it];
            v4f b = tb[it];
            float s = ((a.x + a.y) + (a.z + a.w)) + ((b.x + b.y) + (b.z + b.w));
            int nn = e / CCH;
            float md = mu_direct[nn] + EPS;
            float mf = mu_diffuse[nn] + EPS;
            __builtin_nontemporal_store(__expf(__fdividef(-s, md)), out + e);
            __builtin_nontemporal_store(__expf(__fdividef(-s, mf)), out + nctot + e);
        }
    }
}

// ---------------------------------------------------------------------------
// Fused kernel, software-pipelined + phase-destaggered. grid = (N/64, 2).
// Block = 384 thr / 6 waves, 64 samples, one output slice (y=0 direct,
// y=1 diffuse) + a disjoint 1344-elem tau chunk.
//   Issue order (vmcnt in-order): cons+mu FIRST, then 8 tau nt-loads, so
//   phase A waits only a counted vmcnt and tau stays in flight under the
//   MLP VALU phase (T4/T14).
//   DESTAGGER: odd blocks run phase C (tau->exp->store, independent of A/B)
//   BEFORE phase A; even blocks after. At steady state each CU holds blocks
//   in opposite phases -> HBM and VALU both stay fed (no lockstep bursts).
// ---------------------------------------------------------------------------
__global__ __launch_bounds__(384, 6) void k_fused(
    const float* __restrict__ tau,
    const float* __restrict__ mu_direct,
    const float* __restrict__ mu_diffuse,
    const float* __restrict__ cons,
    const float* __restrict__ Wd0, const float* __restrict__ bd0,
    const float* __restrict__ Wf0, const float* __restrict__ bf0,
    const float* __restrict__ Wd1, const float* __restrict__ bd1,
    const float* __restrict__ Wf1, const float* __restrict__ bf1,
    const float* __restrict__ Wd2, const float* __restrict__ bd2,
    const float* __restrict__ Wf2, const float* __restrict__ bf2,
    const float* __restrict__ Wd3, const float* __restrict__ bd3,
    const float* __restrict__ Wf3, const float* __restrict__ bf3,
    float* __restrict__ out, int N)
{
    __shared__ float es[64 * 127];
    const int tid  = threadIdx.x;
    const int lane = tid & 63;
    const int wave = tid >> 6;
    const int n0   = blockIdx.x * 64;
    const int n    = n0 + lane;
    const bool direct = (blockIdx.y == 0);
    const bool cfirst = (blockIdx.x & 1);
    const size_t nctot = (size_t)N * CCH;

    // ---- Issue the phase-A inputs FIRST (oldest in vmcnt order) ----
    float4 c0 = *(const float4*)(cons + (size_t)n * NCON);
    float4 c1 = *(const float4*)(cons + (size_t)n * NCON + 4);
    float mu  = direct ? mu_direct[n] : 0.0f;
    __builtin_amdgcn_sched_barrier(0);   // pin: cons/mu issue before tau loads

    // ---- Then issue the tau-chunk nt loads (younger; stay in flight) ----
    const int nblk = gridDim.x * 2;
    const int cid  = blockIdx.y * gridDim.x + blockIdx.x;
    const int per  = (int)(nctot / nblk);        // 1344 for N=524288
    const int base_e = cid * per;
    v4f ta[4], tb[4];
#pragma unroll
    for (int it = 0; it < 4; ++it) {
        int off = it * 384 + tid;
        if (off < per) {
            const v4f* t4 = (const v4f*)tau + ((size_t)base_e + off) * 2;
            ta[it] = __builtin_nontemporal_load(t4);
            tb[it] = __builtin_nontemporal_load(t4 + 1);
        }
    }
    __builtin_amdgcn_sched_barrier(0);   // pin: tau loads issued before phases

    // ---- Odd blocks: consume tau chunk now (destagger memory phase) ----
    if (cfirst)
        phase_c(ta, tb, mu_direct, mu_diffuse, out, nctot, base_e, per, tid);

    // ---- Phase A: MLP -> LDS ----
    float x[9] = {c0.x, c0.y, c0.z, c0.w, c1.x, c1.y, c1.z, c1.w, 0.0f};
    if (direct) {
        float inv = __fdividef(1.0f, mu + EPS);
#pragma unroll
        for (int i = 0; i < 8; ++i) x[i] *= inv;
        x[8] = mu;
#pragma unroll 1
        for (int ci = 0; ci < 7; ++ci) {
            int c = __builtin_amdgcn_readfirstlane(wave * 7 + ci);
            float o[3];
            mlp_softmax3<9>(x, c, Wd0, bd0, Wd1, bd1, Wd2, bd2, Wd3, bd3, o);
#pragma unroll
            for (int k = 0; k < 3; ++k) es[lane * 127 + c * 3 + k] = o[k];
        }
    } else {
#pragma unroll 1
        for (int ci = 0; ci < 7; ++ci) {
            int c = __builtin_amdgcn_readfirstlane(wave * 7 + ci);
            float o[3];
            mlp_softmax3<8>(x, c, Wf0, bf0, Wf1, bf1, Wf2, bf2, Wf3, bf3, o);
#pragma unroll
            for (int k = 0; k < 3; ++k) es[lane * 127 + c * 3 + k] = o[k];
        }
    }
    __syncthreads();

    // ---- Phase B: coalesced nt writeout of the 64x126 tile ----
    float* base = out + (direct ? 2 : 5) * nctot + (size_t)n0 * (CCH * 3);
    for (int idx = tid; idx < 64 * 63; idx += 384) {
        int r = idx / 63;
        int q = idx - r * 63;
        v2f v;
        v.x = es[r * 127 + 2 * q];
        v.y = es[r * 127 + 2 * q + 1];
        __builtin_nontemporal_store(v, (v2f*)base + idx);
    }

    // ---- Even blocks: consume tau chunk last ----
    if (!cfirst)
        phase_c(ta, tb, mu_direct, mu_diffuse, out, nctot, base_e, per, tid);
}

extern "C" void kernel_launch(void* const* d_in, const int* in_sizes, int n_in,
                              void* d_out, int out_size, void* d_ws, size_t ws_size,
                              hipStream_t stream) {
    const float* tau  = (const float*)d_in[0];
    const float* mud  = (const float*)d_in[1];
    const float* muf  = (const float*)d_in[2];
    const float* cons = (const float*)d_in[3];
    // setup_inputs() dict order: Wd{i}, bd{i}, Wf{i}, bf{i} interleaved per layer.
    const float* Wd0 = (const float*)d_in[4];  const float* bd0 = (const float*)d_in[5];
    const float* Wf0 = (const float*)d_in[6];  const float* bf0 = (const float*)d_in[7];
    const float* Wd1 = (const float*)d_in[8];  const float* bd1 = (const float*)d_in[9];
    const float* Wf1 = (const float*)d_in[10]; const float* bf1 = (const float*)d_in[11];
    const float* Wd2 = (const float*)d_in[12]; const float* bd2 = (const float*)d_in[13];
    const float* Wf2 = (const float*)d_in[14]; const float* bf2 = (const float*)d_in[15];
    const float* Wd3 = (const float*)d_in[16]; const float* bd3 = (const float*)d_in[17];
    const float* Wf3 = (const float*)d_in[18]; const float* bf3 = (const float*)d_in[19];
    float* out = (float*)d_out;

    int N = in_sizes[1];            // mu_direct element count = N
    dim3 grid(N / 64, 2);
    k_fused<<<grid, 384, 0, stream>>>(tau, mud, muf, cons,
                                      Wd0, bd0, Wf0, bf0,
                                      Wd1, bd1, Wf1, bf1,
                                      Wd2, bd2, Wf2, bf2,
                                      Wd3, bd3, Wf3, bf3,
                                      out, N);
}

// Round 10
// 296.894 us; speedup vs baseline: 1.2494x; 1.0511x over previous
//
#include <hip/hip_runtime.h>

#define EPS 1e-7f
#define CCH 42
#define NCON 8

typedef float v4f __attribute__((ext_vector_type(4)));
typedef float v2f __attribute__((ext_vector_type(2)));

// ---------------------------------------------------------------------------
// Per-channel MLP (dims NIN -> 5 -> 4 -> 4 -> 3) + 3-way softmax.
// `c` is wave-uniform, so weight/bias loads compile to s_load and FMAs take
// the weight operand from SGPRs.
// ---------------------------------------------------------------------------
template<int NIN>
__device__ __forceinline__ void mlp_softmax3(
    const float x[NIN], int c,
    const float* __restrict__ W0, const float* __restrict__ b0,
    const float* __restrict__ W1, const float* __restrict__ b1,
    const float* __restrict__ W2, const float* __restrict__ b2,
    const float* __restrict__ W3, const float* __restrict__ b3,
    float o[3])
{
    float h0[5];
#pragma unroll
    for (int j = 0; j < 5; ++j) {
        const float* w = W0 + (c * 5 + j) * NIN;
        float a = b0[c * 5 + j];
#pragma unroll
        for (int i = 0; i < NIN; ++i) a = fmaf(x[i], w[i], a);
        h0[j] = fmaxf(a, 0.0f);
    }
    float h1[4];
#pragma unroll
    for (int j = 0; j < 4; ++j) {
        const float* w = W1 + (c * 4 + j) * 5;
        float a = b1[c * 4 + j];
#pragma unroll
        for (int i = 0; i < 5; ++i) a = fmaf(h0[i], w[i], a);
        h1[j] = fmaxf(a, 0.0f);
    }
    float h2[4];
#pragma unroll
    for (int j = 0; j < 4; ++j) {
        const float* w = W2 + (c * 4 + j) * 4;
        float a = b2[c * 4 + j];
#pragma unroll
        for (int i = 0; i < 4; ++i) a = fmaf(h1[i], w[i], a);
        h2[j] = fmaxf(a, 0.0f);
    }
    float lg[3];
#pragma unroll
    for (int j = 0; j < 3; ++j) {
        const float* w = W3 + (c * 3 + j) * 4;
        float a = b3[c * 3 + j];
#pragma unroll
        for (int i = 0; i < 4; ++i) a = fmaf(h2[i], w[i], a);
        lg[j] = a;
    }
    float m = fmaxf(fmaxf(lg[0], lg[1]), lg[2]);
    float e0 = __expf(lg[0] - m);
    float e1 = __expf(lg[1] - m);
    float e2 = __expf(lg[2] - m);
    float r = __fdividef(1.0f, e0 + e1 + e2);
    o[0] = e0 * r;
    o[1] = e1 * r;
    o[2] = e2 * r;
}

// One tau batch: STATIC index IT (rule #20 — no runtime indexing into
// ext-vector arrays). mdv/mfv were loaded BEFORE the tau loads, so using
// them waits only on old loads; tau batch IT waits a counted vmcnt with
// younger batches still in flight.
template<int IT>
__device__ __forceinline__ void phase_c_batch(
    const v4f ta[4], const v4f tb[4], const float mdv[4], const float mfv[4],
    float* __restrict__ out, size_t nctot, int base_e, int per, int tid)
{
    int off = IT * 384 + tid;
    if (off < per) {
        int e = base_e + off;
        v4f a = ta[IT];
        v4f b = tb[IT];
        float s = ((a.x + a.y) + (a.z + a.w)) + ((b.x + b.y) + (b.z + b.w));
        float md = mdv[IT] + EPS;
        float mf = mfv[IT] + EPS;
        __builtin_nontemporal_store(__expf(__fdividef(-s, md)), out + e);
        __builtin_nontemporal_store(__expf(__fdividef(-s, mf)), out + nctot + e);
    }
}

// ---------------------------------------------------------------------------
// Fused kernel, software-pipelined + statically interleaved. grid = (N/64, 2).
// Block = 384 thr / 6 waves, 64 samples, one output slice (y=0 direct,
// y=1 diffuse) + the 1344-elem tau chunk covering ITS OWN samples (mu reads
// L1-warm behind the cons loads).
//   Issue order (vmcnt is in-order): cons + mu + phase-C mu's FIRST, then
//   the 8 tau nt-loads. Phase-C batch k is consumed after MLP channel k+2,
//   pinned by sched_barrier(0) -> stores and counted vmcnt waits are spread
//   across the VALU phase instead of bursting at block end.
// ---------------------------------------------------------------------------
__global__ __launch_bounds__(384, 6) void k_fused(
    const float* __restrict__ tau,
    const float* __restrict__ mu_direct,
    const float* __restrict__ mu_diffuse,
    const float* __restrict__ cons,
    const float* __restrict__ Wd0, const float* __restrict__ bd0,
    const float* __restrict__ Wf0, const float* __restrict__ bf0,
    const float* __restrict__ Wd1, const float* __restrict__ bd1,
    const float* __restrict__ Wf1, const float* __restrict__ bf1,
    const float* __restrict__ Wd2, const float* __restrict__ bd2,
    const float* __restrict__ Wf2, const float* __restrict__ bf2,
    const float* __restrict__ Wd3, const float* __restrict__ bd3,
    const float* __restrict__ Wf3, const float* __restrict__ bf3,
    float* __restrict__ out, int N)
{
    __shared__ float es[64 * 127];
    const int tid  = threadIdx.x;
    const int lane = tid & 63;
    const int wave = tid >> 6;
    const int n0   = blockIdx.x * 64;
    const int n    = n0 + lane;
    const bool direct = (blockIdx.y == 0);
    const size_t nctot = (size_t)N * CCH;

    // phase-C chunk: this block's own samples, half per y-slice
    const int per    = 32 * CCH;                               // 1344
    const int base_e = blockIdx.x * (64 * CCH) + (direct ? 0 : per);

    // ---- oldest in vmcnt order: every scalar input phase A or C will touch ----
    float4 c0 = *(const float4*)(cons + (size_t)n * NCON);
    float4 c1 = *(const float4*)(cons + (size_t)n * NCON + 4);
    float mu  = direct ? mu_direct[n] : 0.0f;
    float mdv[4], mfv[4];
#pragma unroll
    for (int it = 0; it < 4; ++it) {
        int off = it * 384 + tid;
        if (off < per) {
            int nn = (base_e + off) / CCH;
            mdv[it] = mu_direct[nn];
            mfv[it] = mu_diffuse[nn];
        }
    }
    __builtin_amdgcn_sched_barrier(0);   // pin: scalar inputs before tau loads

    // ---- then the tau-chunk nt loads (younger; stay in flight) ----
    v4f ta[4], tb[4];
#pragma unroll
    for (int it = 0; it < 4; ++it) {
        int off = it * 384 + tid;
        if (off < per) {
            const v4f* t4 = (const v4f*)tau + ((size_t)base_e + off) * 2;
            ta[it] = __builtin_nontemporal_load(t4);
            tb[it] = __builtin_nontemporal_load(t4 + 1);
        }
    }
    __builtin_amdgcn_sched_barrier(0);   // pin: tau loads issued before phase A

    // ---- Phase A (channels hand-sequenced) + static phase-C interleave ----
    float x[9] = {c0.x, c0.y, c0.z, c0.w, c1.x, c1.y, c1.z, c1.w, 0.0f};
    if (direct) {
        float inv = __fdividef(1.0f, mu + EPS);
#pragma unroll
        for (int i = 0; i < 8; ++i) x[i] *= inv;
        x[8] = mu;
    }
    auto do_ch = [&](int ci) {
        int c = __builtin_amdgcn_readfirstlane(wave * 7 + ci);
        float o[3];
        if (direct)
            mlp_softmax3<9>(x, c, Wd0, bd0, Wd1, bd1, Wd2, bd2, Wd3, bd3, o);
        else
            mlp_softmax3<8>(x, c, Wf0, bf0, Wf1, bf1, Wf2, bf2, Wf3, bf3, o);
#pragma unroll
        for (int k = 0; k < 3; ++k) es[lane * 127 + c * 3 + k] = o[k];
    };

    do_ch(0);
    do_ch(1);
    do_ch(2);
    phase_c_batch<0>(ta, tb, mdv, mfv, out, nctot, base_e, per, tid);
    __builtin_amdgcn_sched_barrier(0);
    do_ch(3);
    phase_c_batch<1>(ta, tb, mdv, mfv, out, nctot, base_e, per, tid);
    __builtin_amdgcn_sched_barrier(0);
    do_ch(4);
    phase_c_batch<2>(ta, tb, mdv, mfv, out, nctot, base_e, per, tid);
    __builtin_amdgcn_sched_barrier(0);
    do_ch(5);
    phase_c_batch<3>(ta, tb, mdv, mfv, out, nctot, base_e, per, tid);
    __builtin_amdgcn_sched_barrier(0);
    do_ch(6);
    __syncthreads();

    // ---- Phase B: coalesced nt writeout of the 64x126 tile ----
    float* base = out + (direct ? 2 : 5) * nctot + (size_t)n0 * (CCH * 3);
    for (int idx = tid; idx < 64 * 63; idx += 384) {
        int r = idx / 63;
        int q = idx - r * 63;
        v2f v;
        v.x = es[r * 127 + 2 * q];
        v.y = es[r * 127 + 2 * q + 1];
        __builtin_nontemporal_store(v, (v2f*)base + idx);
    }
}

extern "C" void kernel_launch(void* const* d_in, const int* in_sizes, int n_in,
                              void* d_out, int out_size, void* d_ws, size_t ws_size,
                              hipStream_t stream) {
    const float* tau  = (const float*)d_in[0];
    const float* mud  = (const float*)d_in[1];
    const float* muf  = (const float*)d_in[2];
    const float* cons = (const float*)d_in[3];
    // setup_inputs() dict order: Wd{i}, bd{i}, Wf{i}, bf{i} interleaved per layer.
    const float* Wd0 = (const float*)d_in[4];  const float* bd0 = (const float*)d_in[5];
    const float* Wf0 = (const float*)d_in[6];  const float* bf0 = (const float*)d_in[7];
    const float* Wd1 = (const float*)d_in[8];  const float* bd1 = (const float*)d_in[9];
    const float* Wf1 = (const float*)d_in[10]; const float* bf1 = (const float*)d_in[11];
    const float* Wd2 = (const float*)d_in[12]; const float* bd2 = (const float*)d_in[13];
    const float* Wf2 = (const float*)d_in[14]; const float* bf2 = (const float*)d_in[15];
    const float* Wd3 = (const float*)d_in[16]; const float* bd3 = (const float*)d_in[17];
    const float* Wf3 = (const float*)d_in[18]; const float* bf3 = (const float*)d_in[19];
    float* out = (float*)d_out;

    int N = in_sizes[1];            // mu_direct element count = N
    dim3 grid(N / 64, 2);
    k_fused<<<grid, 384, 0, stream>>>(tau, mud, muf, cons,
                                      Wd0, bd0, Wf0, bf0,
                                      Wd1, bd1, Wf1, bf1,
                                      Wd2, bd2, Wf2, bf2,
                                      Wd3, bd3, Wf3, bf3,
                                      out, N);
}